// Round 1
// baseline (87.043 us; speedup 1.0000x reference)
//
#include <hip/hip_runtime.h>

#define B 4
#define L 512
#define H 768
#define S 100
#define R 100
#define E 25
#define NE 10
#define NR 6
#define NEGF (-1e20f)

// ---------------------------------------------------------------------------
// K1: masked max-pool for entity spans (j < S) and relation contexts (j >= S).
// Span blocks also write size-embedding rows and fuse the entity-logit GEMV.
// grid = B*(S+R), block = 256 (= 4 waves of 64)
// ---------------------------------------------------------------------------
__global__ __launch_bounds__(256) void pool_kernel(
    const float* __restrict__ hidden,     // (B, L, H)
    const int*   __restrict__ emask,      // (B, S, L)
    const int*   __restrict__ cmask,      // (B, R, L)
    const float* __restrict__ size_emb,   // (MAXLEN, E)
    const float* __restrict__ w_span,     // (H+E, NE)
    const float* __restrict__ b_span,     // (NE,)
    float* __restrict__ entities,         // ws: (B, S, H)
    float* __restrict__ sizes,            // ws: (B, S, E)
    float* __restrict__ rel_ctx,          // ws: (B, R, H)
    float* __restrict__ ent_logits)       // out: (B, S, NE)
{
    const int idx = blockIdx.x;
    const int b = idx / (S + R);
    const int j = idx % (S + R);
    const bool is_span = (j < S);

    __shared__ int   poss[L];
    __shared__ int   s_cnt;
    __shared__ float s_red[4][NE];

    if (threadIdx.x == 0) s_cnt = 0;
    __syncthreads();

    // Compact active mask positions into LDS (order irrelevant for max/count).
    const int* mrow = is_span ? (emask + (size_t)(b * S + j) * L)
                              : (cmask + (size_t)(b * R + (j - S)) * L);
    for (int l = (int)threadIdx.x; l < L; l += 256) {
        if (mrow[l] != 0) {
            int p = atomicAdd(&s_cnt, 1);
            poss[p] = l;
        }
    }
    __syncthreads();
    const int n = s_cnt;

    // Each thread max-pools 3 channels; consecutive lanes -> consecutive h
    // (coalesced reads of hidden).
    const int h0 = threadIdx.x, h1 = threadIdx.x + 256, h2 = threadIdx.x + 512;
    float mv0 = NEGF, mv1 = NEGF, mv2 = NEGF;
    const float* hb = hidden + (size_t)b * L * H;
    for (int i = 0; i < n; ++i) {
        const float* hp = hb + (size_t)poss[i] * H;
        mv0 = fmaxf(mv0, hp[h0]);
        mv1 = fmaxf(mv1, hp[h1]);
        mv2 = fmaxf(mv2, hp[h2]);
    }

    if (!is_span) {
        const int r = j - S;
        float* orow = rel_ctx + (size_t)(b * R + r) * H;
        orow[h0] = mv0; orow[h1] = mv1; orow[h2] = mv2;
        return;
    }

    const int s = j;
    float* erow = entities + (size_t)(b * S + s) * H;
    erow[h0] = mv0; erow[h1] = mv1; erow[h2] = mv2;

    // entity_sizes = size_emb[sum(mask)]  (n < MAXLEN guaranteed by harness)
    const float* srow_src = size_emb + (size_t)n * E;
    float* srow = sizes + (size_t)(b * S + s) * E;
    if (threadIdx.x < E) srow[threadIdx.x] = srow_src[threadIdx.x];

    // Fused entity logits: logit[o] = sum_h e[h]*w_span[h,o]
    //                               + sum_e sz[e]*w_span[H+e,o] + b_span[o]
    float p[NE];
    #pragma unroll
    for (int o = 0; o < NE; ++o)
        p[o] = mv0 * w_span[(size_t)h0 * NE + o]
             + mv1 * w_span[(size_t)h1 * NE + o]
             + mv2 * w_span[(size_t)h2 * NE + o];

    #pragma unroll
    for (int o = 0; o < NE; ++o) {
        float v = p[o];
        for (int off = 32; off > 0; off >>= 1) v += __shfl_down(v, off, 64);
        p[o] = v;
    }
    const int wave = threadIdx.x >> 6;
    const int lane = threadIdx.x & 63;
    if (lane == 0) {
        #pragma unroll
        for (int o = 0; o < NE; ++o) s_red[wave][o] = p[o];
    }
    __syncthreads();
    if (threadIdx.x < NE) {
        const int o = threadIdx.x;
        float v = s_red[0][o] + s_red[1][o] + s_red[2][o] + s_red[3][o];
        #pragma unroll
        for (int e = 0; e < E; ++e)
            v += srow_src[e] * w_span[(size_t)(H + e) * NE + o];
        v += b_span[o];
        ent_logits[(size_t)(b * S + s) * NE + o] = v;
    }
}

// ---------------------------------------------------------------------------
// K2: relation logits. rel_repr = [ctx(768) | e_head(768) | e_tail(768) |
//                                  sz_head(25) | sz_tail(25)]  (D = 2354)
// grid = B*R, block = 256
// ---------------------------------------------------------------------------
__global__ __launch_bounds__(256) void rel_kernel(
    const float* __restrict__ entities,   // (B, S, H)
    const float* __restrict__ sizes,      // (B, S, E)
    const float* __restrict__ rel_ctx,    // (B, R, H)
    const int*   __restrict__ relations,  // (B, R, 2)
    const float* __restrict__ w_rel,      // (3H+2E, NR)
    const float* __restrict__ b_rel,      // (NR,)
    float* __restrict__ rel_logits)       // out: (B, R, NR)
{
    const int idx = blockIdx.x;
    const int b = idx / R;
    const int r = idx % R;
    const int head = relations[(size_t)(b * R + r) * 2 + 0];
    const int tail = relations[(size_t)(b * R + r) * 2 + 1];

    const float* ctx = rel_ctx  + (size_t)(b * R + r)    * H;
    const float* eh  = entities + (size_t)(b * S + head) * H;
    const float* et  = entities + (size_t)(b * S + tail) * H;
    const float* sh  = sizes    + (size_t)(b * S + head) * E;
    const float* st  = sizes    + (size_t)(b * S + tail) * E;

    const int D = 3 * H + 2 * E;  // 2354
    float p[NR] = {0.f, 0.f, 0.f, 0.f, 0.f, 0.f};
    for (int i = (int)threadIdx.x; i < D; i += 256) {
        float x;
        if      (i < H)         x = ctx[i];
        else if (i < 2 * H)     x = eh[i - H];
        else if (i < 3 * H)     x = et[i - 2 * H];
        else if (i < 3 * H + E) x = sh[i - 3 * H];
        else                    x = st[i - 3 * H - E];
        const float* wr = w_rel + (size_t)i * NR;
        #pragma unroll
        for (int o = 0; o < NR; ++o) p[o] += x * wr[o];
    }

    __shared__ float s_red[4][NR];
    #pragma unroll
    for (int o = 0; o < NR; ++o) {
        float v = p[o];
        for (int off = 32; off > 0; off >>= 1) v += __shfl_down(v, off, 64);
        p[o] = v;
    }
    const int wave = threadIdx.x >> 6;
    const int lane = threadIdx.x & 63;
    if (lane == 0) {
        #pragma unroll
        for (int o = 0; o < NR; ++o) s_red[wave][o] = p[o];
    }
    __syncthreads();
    if (threadIdx.x < NR) {
        const int o = threadIdx.x;
        float v = s_red[0][o] + s_red[1][o] + s_red[2][o] + s_red[3][o] + b_rel[o];
        rel_logits[(size_t)(b * R + r) * NR + o] = v;
    }
}

extern "C" void kernel_launch(void* const* d_in, const int* in_sizes, int n_in,
                              void* d_out, int out_size, void* d_ws, size_t ws_size,
                              hipStream_t stream) {
    const float* hidden    = (const float*)d_in[0];
    const int*   emask     = (const int*)  d_in[1];
    const int*   relations = (const int*)  d_in[2];
    const int*   cmask     = (const int*)  d_in[3];
    const float* size_emb  = (const float*)d_in[4];
    const float* w_span    = (const float*)d_in[5];
    const float* b_span    = (const float*)d_in[6];
    const float* w_rel     = (const float*)d_in[7];
    const float* b_rel     = (const float*)d_in[8];

    float* out        = (float*)d_out;
    float* ent_logits = out;                 // (B, S, NE) = 4000 floats
    float* rel_logits = out + B * S * NE;    // (B, R, NR) = 2400 floats

    float* ws       = (float*)d_ws;
    float* entities = ws;                          // B*S*H
    float* sizes    = entities + (size_t)B * S * H; // B*S*E
    float* rel_ctx  = sizes + (size_t)B * S * E;    // B*R*H

    pool_kernel<<<B * (S + R), 256, 0, stream>>>(
        hidden, emask, cmask, size_emb, w_span, b_span,
        entities, sizes, rel_ctx, ent_logits);

    rel_kernel<<<B * R, 256, 0, stream>>>(
        entities, sizes, rel_ctx, relations, w_rel, b_rel, rel_logits);
}